// Round 10
// baseline (75.950 us; speedup 1.0000x reference)
//
#include <hip/hip_runtime.h>
#include <hip/hip_bf16.h>

#define M_ROWS 8192
#define HALF_N 4096
#define D 128
#define NT 4             // tiles (64 cols each) per block
#define E2C 2.8853900817779268f   // INV_T(=2) * log2(e)

typedef __attribute__((ext_vector_type(4))) float f32x4;
typedef __attribute__((ext_vector_type(8))) short bf16x8;
typedef unsigned int u32;
typedef __attribute__((ext_vector_type(4))) u32 u32x4;

// ---------------------------------------------------------------------------
// Kernel A: L2-normalize rows (fp32 in, bf16 out), zero rowsum accumulator.
// ---------------------------------------------------------------------------
__global__ __launch_bounds__(256) void k_normalize(
    const float* __restrict__ zi, const float* __restrict__ zj,
    __hip_bfloat16* __restrict__ zb, float* __restrict__ rowsum)
{
    int t = blockIdx.x * 256 + threadIdx.x;
    if (t < M_ROWS) rowsum[t] = 0.0f;   // re-init every launch (ws not re-poisoned)

    int row  = t >> 6;
    int lane = t & 63;
    const float* src = (row < HALF_N) ? (zi + (size_t)row * D)
                                      : (zj + (size_t)(row - HALF_N) * D);
    float2 v = *(const float2*)(src + lane * 2);
    float ss = v.x * v.x + v.y * v.y;
    #pragma unroll
    for (int o = 32; o >= 1; o >>= 1) ss += __shfl_xor(ss, o);
    float scale = 1.0f / fmaxf(sqrtf(ss), 1e-12f);

    __hip_bfloat162 o2;
    o2.x = __float2bfloat16(v.x * scale);
    o2.y = __float2bfloat16(v.y * scale);
    *(__hip_bfloat162*)(zb + (size_t)row * D + lane * 2) = o2;
}

// ---------------------------------------------------------------------------
// Kernel B: round-4 proven skeleton, tile width 128 -> 64 cols.
// Block (chunk, pi) computes sim rows [pi*128,+128) x cols [chunk*256,+256)
// as 4 tiles of 128rows x 64cols. A-tile (32 rows x K128 per wave) in 32
// VGPRs; B-tiles (64 simcols x K128 = 16KB) double-buffered in LDS,
// reg-staged (coalesced loads prefetched 1 tile ahead, swizzled ds_write),
// two barriers per tile. 32KB LDS + ~80 VGPR -> 4 blocks/CU (vs round 4's
// 2): same pipe work, twice the waves to hide barrier/LDS stalls.
// exp sums accumulate in registers; 128 atomics per block at the end.
// ---------------------------------------------------------------------------
__global__ __launch_bounds__(256, 4) void k_simsum(
    const __hip_bfloat16* __restrict__ zb, float* __restrict__ rowsum)
{
    __shared__ char sB[2][16384];       // two 64x128 bf16 B-tiles

    const int chunk = blockIdx.x;             // 0..31
    const int pi    = blockIdx.y;             // 0..63
    const int ibase = pi * 128;
    const int jbase = chunk * (NT * 64);      // 256 cols per block
    const int tid   = threadIdx.x;
    const int wv    = tid >> 6, lane = tid & 63;
    const int lr    = lane & 15, lg = lane >> 4;
    const int rbase = wv * 32;

    // A fragments: 32 rows x K=128 per wave, in 32 VGPRs (from L2).
    bf16x8 a[2][4];
    #pragma unroll
    for (int m = 0; m < 2; ++m)
        #pragma unroll
        for (int ks = 0; ks < 4; ++ks) {
            int row = ibase + rbase + m * 16 + lr;
            a[m][ks] = *(const bf16x8*)(zb + (size_t)row * D + (ks * 4 + lg) * 8);
        }

    // Reg-staged B tile (16KB = 64B/thread): linear loads, swizzled ds_write.
    u32x4 breg[4];
    auto load_tile = [&](int t) {
        const __hip_bfloat16* src = zb + (size_t)(jbase + t * 64) * D;
        #pragma unroll
        for (int i = 0; i < 4; ++i) {
            int row = (wv * 4 + i) * 4 + lg;          // 0..63
            breg[i] = *(const u32x4*)(src + (size_t)row * D + lr * 8);
        }
    };
    auto write_tile = [&](char* buf) {
        #pragma unroll
        for (int i = 0; i < 4; ++i) {
            int row = (wv * 4 + i) * 4 + lg;
            *(u32x4*)(buf + row * 256 + ((lr ^ (row & 7)) << 4)) = breg[i];
        }
    };

    float eacc[2][4] = {{0.f, 0.f, 0.f, 0.f}, {0.f, 0.f, 0.f, 0.f}};

    load_tile(0);
    write_tile(sB[0]);
    __syncthreads();

    for (int t = 0; t < NT; ++t) {
        if (t + 1 < NT) load_tile(t + 1);   // prefetch to regs under compute
        const char* cur = sB[t & 1];

        f32x4 acc[2][4];
        #pragma unroll
        for (int m = 0; m < 2; ++m)
            #pragma unroll
            for (int n = 0; n < 4; ++n) acc[m][n] = (f32x4){0.f, 0.f, 0.f, 0.f};

        #pragma unroll
        for (int ks = 0; ks < 4; ++ks) {
            #pragma unroll
            for (int n = 0; n < 4; ++n) {
                int rowB = n * 16 + lr;                    // 0..63
                bf16x8 bfr = *(const bf16x8*)(cur + rowB * 256 +
                              ((((ks << 2) + lg) ^ (lr & 7)) << 4));
                acc[0][n] = __builtin_amdgcn_mfma_f32_16x16x32_bf16(a[0][ks], bfr, acc[0][n], 0, 0, 0);
                acc[1][n] = __builtin_amdgcn_mfma_f32_16x16x32_bf16(a[1][ks], bfr, acc[1][n], 0, 0, 0);
            }
        }

        #pragma unroll
        for (int m = 0; m < 2; ++m)
            #pragma unroll
            for (int n = 0; n < 4; ++n)
                #pragma unroll
                for (int r = 0; r < 4; ++r)
                    eacc[m][r] += exp2f(acc[m][n][r] * E2C);

        __syncthreads();                     // everyone done reading cur
        if (t + 1 < NT) {
            write_tile(sB[(t + 1) & 1]);     // fill the other buffer
            __syncthreads();                 // writes visible before compute
        }
    }

    // Epilogue: reduce over the 16 col-lanes, one atomic per row.
    #pragma unroll
    for (int m = 0; m < 2; ++m)
        #pragma unroll
        for (int r = 0; r < 4; ++r) {
            float e = eacc[m][r];
            e += __shfl_xor(e, 1);
            e += __shfl_xor(e, 2);
            e += __shfl_xor(e, 4);
            e += __shfl_xor(e, 8);
            if (lr == 0)
                atomicAdd(&rowsum[ibase + rbase + m * 16 + lg * 4 + r], e);
        }
}

// ---------------------------------------------------------------------------
// Kernel C: per row, recompute self-dot and positive-pair dot (fp32 from
// bf16), lse = log(rowsum - exp(2*self) + exp(2*pos)), write lse - pos.
// ---------------------------------------------------------------------------
__global__ __launch_bounds__(256) void k_rowloss(
    const __hip_bfloat16* __restrict__ zb, const float* __restrict__ rowsum,
    float* __restrict__ rowloss)
{
    int t = blockIdx.x * 256 + threadIdx.x;
    int row = t >> 6, lane = t & 63;
    int pair = row ^ HALF_N;

    __hip_bfloat162 av = *(const __hip_bfloat162*)(zb + (size_t)row  * D + lane * 2);
    __hip_bfloat162 bv = *(const __hip_bfloat162*)(zb + (size_t)pair * D + lane * 2);
    float ax = __bfloat162float(av.x), ay = __bfloat162float(av.y);
    float bx = __bfloat162float(bv.x), by = __bfloat162float(bv.y);
    float sd = ax * ax + ay * ay;
    float pd = ax * bx + ay * by;
    #pragma unroll
    for (int o = 32; o >= 1; o >>= 1) {
        sd += __shfl_xor(sd, o);
        pd += __shfl_xor(pd, o);
    }
    if (lane == 0) {
        float rs  = rowsum[row];
        float val = rs - exp2f(sd * E2C) + exp2f(pd * E2C);
        rowloss[row] = logf(val) - 2.0f * pd;
    }
}

// ---------------------------------------------------------------------------
// Kernel D: single-block tree reduction of rowloss[8192] -> mean.
// ---------------------------------------------------------------------------
__global__ __launch_bounds__(1024) void k_reduce(
    const float* __restrict__ rowloss, float* __restrict__ out)
{
    __shared__ float sm[16];
    int tid = threadIdx.x;
    float s = 0.f;
    #pragma unroll
    for (int i = 0; i < M_ROWS / 1024; ++i) s += rowloss[i * 1024 + tid];
    #pragma unroll
    for (int o = 32; o >= 1; o >>= 1) s += __shfl_xor(s, o);
    if ((tid & 63) == 0) sm[tid >> 6] = s;
    __syncthreads();
    if (tid == 0) {
        float tot = 0.f;
        #pragma unroll
        for (int w = 0; w < 16; ++w) tot += sm[w];
        out[0] = tot * (1.0f / (float)M_ROWS);
    }
}

// ---------------------------------------------------------------------------
extern "C" void kernel_launch(void* const* d_in, const int* in_sizes, int n_in,
                              void* d_out, int out_size, void* d_ws, size_t ws_size,
                              hipStream_t stream)
{
    const float* zi = (const float*)d_in[0];
    const float* zj = (const float*)d_in[1];

    float* rowsum  = (float*)d_ws;                               // 8192 f32
    float* rowloss = rowsum + M_ROWS;                            // 8192 f32
    __hip_bfloat16* zb = (__hip_bfloat16*)((char*)d_ws + 65536); // 8192x128 bf16

    k_normalize<<<dim3(M_ROWS * 64 / 256), 256, 0, stream>>>(zi, zj, zb, rowsum);
    k_simsum<<<dim3(32, 64), dim3(256), 0, stream>>>(zb, rowsum);
    k_rowloss<<<dim3(M_ROWS * 64 / 256), 256, 0, stream>>>(zb, rowsum, rowloss);
    k_reduce<<<dim3(1), dim3(1024), 0, stream>>>(rowloss, (float*)d_out);
}

// Round 11
// 49.776 us; speedup vs baseline: 1.5258x; 1.5258x over previous
//
#include <hip/hip_runtime.h>
#include <hip/hip_bf16.h>

#define M_ROWS 8192
#define HALF_N 4096
#define D 128
#define NT 4             // tiles (128 cols) per block
#define NPART 32         // 16 chunks x 2 col-half-waves
#define E2C 2.8853900817779268f   // INV_T(=2) * log2(e)

typedef __attribute__((ext_vector_type(4))) float f32x4;
typedef __attribute__((ext_vector_type(8))) short bf16x8;
typedef unsigned int u32;
typedef __attribute__((ext_vector_type(4))) u32 u32x4;

// ---------------------------------------------------------------------------
// Kernel A: L2-normalize rows (fp32 in, bf16 out).
// ---------------------------------------------------------------------------
__global__ __launch_bounds__(256) void k_normalize(
    const float* __restrict__ zi, const float* __restrict__ zj,
    __hip_bfloat16* __restrict__ zb)
{
    int t = blockIdx.x * 256 + threadIdx.x;
    int row  = t >> 6;
    int lane = t & 63;
    const float* src = (row < HALF_N) ? (zi + (size_t)row * D)
                                      : (zj + (size_t)(row - HALF_N) * D);
    float2 v = *(const float2*)(src + lane * 2);
    float ss = v.x * v.x + v.y * v.y;
    #pragma unroll
    for (int o = 32; o >= 1; o >>= 1) ss += __shfl_xor(ss, o);
    float scale = 1.0f / fmaxf(sqrtf(ss), 1e-12f);

    __hip_bfloat162 o2;
    o2.x = __float2bfloat16(v.x * scale);
    o2.y = __float2bfloat16(v.y * scale);
    *(__hip_bfloat162*)(zb + (size_t)row * D + lane * 2) = o2;
}

// ---------------------------------------------------------------------------
// Kernel B: block (chunk, pi) computes sim rows [pi*128,+128) x cols
// [chunk*512,+512) — 4 tiles, reg-staged double buffer, TWO barriers/tile.
// 2x2 wave mapping: wave (wm,wn) owns rows wm*64+[0,64) x cols wn*64+[0,64),
// so each wave reads only its B-quarter from LDS (halves LDS pipe traffic,
// the dominant per-block cost). A (64 rows x K128/wave) in 64 VGPRs.
// NO VGPR cap (plain launch_bounds(256)): the ~200-VGPR working set fits
// without spill; occupancy is LDS-bound at 2 blocks/CU either way.
// exp sums accumulate in regs; plain store to owned rspart slot (no atomics).
// ---------------------------------------------------------------------------
__global__ __launch_bounds__(256) void k_simsum(
    const __hip_bfloat16* __restrict__ zb, float* __restrict__ rspart)
{
    __shared__ char sB[2][32768];

    const int chunk = blockIdx.x;            // 0..15
    const int pi    = blockIdx.y;            // 0..63
    const int ibase = pi * 128;
    const int jbase = chunk * (NT * 128);
    const int tid   = threadIdx.x;
    const int wv    = tid >> 6, lane = tid & 63;
    const int wm    = wv >> 1,  wn   = wv & 1;
    const int lr    = lane & 15, lg = lane >> 4;

    // A fragments: 64 rows x K=128 per wave, in 64 VGPRs (from L2).
    bf16x8 a[4][4];
    #pragma unroll
    for (int m = 0; m < 4; ++m)
        #pragma unroll
        for (int ks = 0; ks < 4; ++ks) {
            int row = ibase + wm * 64 + m * 16 + lr;
            a[m][ks] = *(const bf16x8*)(zb + (size_t)row * D + (ks * 4 + lg) * 8);
        }

    // Reg-staged B tile: linear coalesced loads, swizzled ds_write.
    u32x4 breg[8];
    auto load_tile = [&](int t) {
        const __hip_bfloat16* src = zb + (size_t)(jbase + t * 128) * D;
        #pragma unroll
        for (int i = 0; i < 8; ++i) {
            int row = (wv * 8 + i) * 4 + lg;
            breg[i] = *(const u32x4*)(src + (size_t)row * D + lr * 8);
        }
    };
    auto write_tile = [&](char* buf) {
        #pragma unroll
        for (int i = 0; i < 8; ++i) {
            int row = (wv * 8 + i) * 4 + lg;
            *(u32x4*)(buf + row * 256 + ((lr ^ (row & 7)) << 4)) = breg[i];
        }
    };

    float eacc[4][4];
    #pragma unroll
    for (int m = 0; m < 4; ++m)
        #pragma unroll
        for (int r = 0; r < 4; ++r) eacc[m][r] = 0.f;

    load_tile(0);
    write_tile(sB[0]);
    __syncthreads();

    for (int t = 0; t < NT; ++t) {
        if (t + 1 < NT) load_tile(t + 1);    // prefetch to regs under compute
        const char* cur = sB[t & 1];

        f32x4 acc[4][4];
        #pragma unroll
        for (int m = 0; m < 4; ++m)
            #pragma unroll
            for (int n = 0; n < 4; ++n) acc[m][n] = (f32x4){0.f, 0.f, 0.f, 0.f};

        #pragma unroll
        for (int ks = 0; ks < 4; ++ks) {
            #pragma unroll
            for (int n = 0; n < 4; ++n) {
                int rowB = wn * 64 + n * 16 + lr;
                bf16x8 bfr = *(const bf16x8*)(cur + rowB * 256 +
                              ((((ks << 2) + lg) ^ (lr & 7)) << 4));
                #pragma unroll
                for (int m = 0; m < 4; ++m)
                    acc[m][n] = __builtin_amdgcn_mfma_f32_16x16x32_bf16(a[m][ks], bfr, acc[m][n], 0, 0, 0);
            }
        }

        #pragma unroll
        for (int m = 0; m < 4; ++m)
            #pragma unroll
            for (int n = 0; n < 4; ++n)
                #pragma unroll
                for (int r = 0; r < 4; ++r)
                    eacc[m][r] += exp2f(acc[m][n][r] * E2C);

        __syncthreads();                     // everyone done reading cur
        if (t + 1 < NT) {
            write_tile(sB[(t + 1) & 1]);     // fill the other buffer
            __syncthreads();                 // writes visible before compute
        }
    }

    // Epilogue: reduce over the 16 col-lanes (this wave's 64-col strip);
    // plain store to the (chunk, wn)-owned partial slot. No atomics.
    #pragma unroll
    for (int m = 0; m < 4; ++m)
        #pragma unroll
        for (int r = 0; r < 4; ++r) {
            float e = eacc[m][r];
            e += __shfl_xor(e, 1);
            e += __shfl_xor(e, 2);
            e += __shfl_xor(e, 4);
            e += __shfl_xor(e, 8);
            if (lr == 0)
                rspart[(chunk * 2 + wn) * M_ROWS +
                       ibase + wm * 64 + m * 16 + lg * 4 + r] = e;
        }
}

// ---------------------------------------------------------------------------
// Kernel C: per row, sum the 32 partials, recompute self/pair dots (fp32
// from bf16), lse = log(total - exp(2*self) + exp(2*pos)), write lse - pos.
// ---------------------------------------------------------------------------
__global__ __launch_bounds__(256) void k_rowloss(
    const __hip_bfloat16* __restrict__ zb, const float* __restrict__ rspart,
    float* __restrict__ rowloss)
{
    int t = blockIdx.x * 256 + threadIdx.x;
    int row = t >> 6, lane = t & 63;
    int pair = row ^ HALF_N;

    float rs = (lane < NPART) ? rspart[lane * M_ROWS + row] : 0.f;

    __hip_bfloat162 av = *(const __hip_bfloat162*)(zb + (size_t)row  * D + lane * 2);
    __hip_bfloat162 bv = *(const __hip_bfloat162*)(zb + (size_t)pair * D + lane * 2);
    float ax = __bfloat162float(av.x), ay = __bfloat162float(av.y);
    float bx = __bfloat162float(bv.x), by = __bfloat162float(bv.y);
    float sd = ax * ax + ay * ay;
    float pd = ax * bx + ay * by;
    #pragma unroll
    for (int o = 32; o >= 1; o >>= 1) {
        sd += __shfl_xor(sd, o);
        pd += __shfl_xor(pd, o);
        rs += __shfl_xor(rs, o);
    }
    if (lane == 0) {
        float val = rs - exp2f(sd * E2C) + exp2f(pd * E2C);
        rowloss[row] = logf(val) - 2.0f * pd;
    }
}

// ---------------------------------------------------------------------------
// Kernel D: single-block tree reduction of rowloss[8192] -> mean.
// ---------------------------------------------------------------------------
__global__ __launch_bounds__(1024) void k_reduce(
    const float* __restrict__ rowloss, float* __restrict__ out)
{
    __shared__ float sm[16];
    int tid = threadIdx.x;
    float s = 0.f;
    #pragma unroll
    for (int i = 0; i < M_ROWS / 1024; ++i) s += rowloss[i * 1024 + tid];
    #pragma unroll
    for (int o = 32; o >= 1; o >>= 1) s += __shfl_xor(s, o);
    if ((tid & 63) == 0) sm[tid >> 6] = s;
    __syncthreads();
    if (tid == 0) {
        float tot = 0.f;
        #pragma unroll
        for (int w = 0; w < 16; ++w) tot += sm[w];
        out[0] = tot * (1.0f / (float)M_ROWS);
    }
}

// ---------------------------------------------------------------------------
extern "C" void kernel_launch(void* const* d_in, const int* in_sizes, int n_in,
                              void* d_out, int out_size, void* d_ws, size_t ws_size,
                              hipStream_t stream)
{
    const float* zi = (const float*)d_in[0];
    const float* zj = (const float*)d_in[1];

    float* rspart  = (float*)d_ws;                                   // 32*8192 f32 = 1MB
    float* rowloss = (float*)((char*)d_ws + 1048576);                // 8192 f32
    __hip_bfloat16* zb = (__hip_bfloat16*)((char*)d_ws + 1048576 + 32768); // 2MB

    k_normalize<<<dim3(M_ROWS * 64 / 256), 256, 0, stream>>>(zi, zj, zb);
    k_simsum<<<dim3(16, 64), dim3(256), 0, stream>>>(zb, rspart);
    k_rowloss<<<dim3(M_ROWS * 64 / 256), 256, 0, stream>>>(zb, rspart, rowloss);
    k_reduce<<<dim3(1), dim3(1024), 0, stream>>>(rowloss, (float*)d_out);
}